// Round 1
// 1086.050 us; speedup vs baseline: 1.1591x; 1.1591x over previous
//
#include <hip/hip_runtime.h>

#define N_ROWS 8192
#define DIM 1024
#define S_DIM 16

typedef __attribute__((ext_vector_type(8))) __bf16 bf16x8;
typedef __attribute__((ext_vector_type(4))) float f32x4;

__device__ __forceinline__ unsigned short f2bf(float f) {
  union { float f; unsigned u; } v; v.f = f;
  unsigned r = v.u + 0x7FFFu + ((v.u >> 16) & 1u);   // round-to-nearest-even
  return (unsigned short)(r >> 16);
}
__device__ __forceinline__ float bf2f(unsigned short b) {
  union { unsigned u; float f; } v; v.u = ((unsigned)b) << 16;
  return v.f;
}

// ---- prep: fp32 -> bf16 (vectorized) ----
__global__ void cvt_bf16_k(const float* __restrict__ src,
                           unsigned short* __restrict__ dst, int n4) {
  int i = blockIdx.x * blockDim.x + threadIdx.x;
  if (i >= n4) return;
  float4 v = ((const float4*)src)[i];
  ushort4 o;
  o.x = f2bf(v.x); o.y = f2bf(v.y); o.z = f2bf(v.z); o.w = f2bf(v.w);
  ((ushort4*)dst)[i] = o;
}

// ---- prep: A_cont = -exp(log_A) ----
__global__ void acont_k(const float* __restrict__ la, float* __restrict__ ac, int n) {
  int i = blockIdx.x * blockDim.x + threadIdx.x;
  if (i < n) ac[i] = -__expf(la[i]);
}

// ---- GEMM: P = act(X @ W'^T + bias), W' = [Wd; Wg] stacked (2048 x 1024) ----
// out layout: row n occupies ushort [n*2048 .. n*2048+2048): first 1024 = delta
// (softplus, cols 0..1023), next 1024 = gate (silu, cols 1024..2047).
// Stacked-W output column j' maps directly to out[n*2048 + j'].
__global__ __launch_bounds__(256) void gemm_act_k(
    const unsigned short* __restrict__ X,      // N x 1024 bf16
    const unsigned short* __restrict__ W,      // 2048 x 1024 bf16 (Wd rows then Wg rows)
    const float* __restrict__ bias_d,
    const float* __restrict__ bias_g,
    unsigned short* __restrict__ outdg)
{
  __shared__ unsigned short As[128][40];     // 32 k + 8 pad (keeps 16B align, breaks pow2 stride)
  __shared__ unsigned short Bs[128][40];

  const int tid  = threadIdx.x;
  const int lane = tid & 63;
  const int wave = tid >> 6;
  const int qr = (wave >> 1) * 64;           // wave quadrant within 128x128
  const int qc = (wave & 1) * 64;
  const int bj = blockIdx.x * 128;           // output-feature tile (0..1920, over 2048 cols)
  const int bn = blockIdx.y * 128;           // row tile
  const int actq = (bj >= 1024);             // uniform per block: 0 softplus, 1 silu

  f32x4 acc[4][4];
  #pragma unroll
  for (int i = 0; i < 4; i++)
    #pragma unroll
    for (int j = 0; j < 4; j++)
      acc[i][j] = (f32x4){0.f, 0.f, 0.f, 0.f};

  const int sr = tid >> 2;                   // staging row 0..63 (and +64)
  const int so = (tid & 3) * 8;              // staging k-offset in bf16
  const unsigned short* Xa = X + (size_t)(bn + sr) * DIM + so;
  const unsigned short* Xb = X + (size_t)(bn + sr + 64) * DIM + so;
  const unsigned short* Wa = W + (size_t)(bj + sr) * DIM + so;
  const unsigned short* Wb = W + (size_t)(bj + sr + 64) * DIM + so;

  const int rl = lane & 15;
  const int kq = (lane >> 4) * 8;

  for (int k0 = 0; k0 < DIM; k0 += 32) {
    int4 a0 = *(const int4*)(Xa + k0);
    int4 a1 = *(const int4*)(Xb + k0);
    int4 b0 = *(const int4*)(Wa + k0);
    int4 b1 = *(const int4*)(Wb + k0);
    __syncthreads();
    *(int4*)&As[sr][so]      = a0;
    *(int4*)&As[sr + 64][so] = a1;
    *(int4*)&Bs[sr][so]      = b0;
    *(int4*)&Bs[sr + 64][so] = b1;
    __syncthreads();

    bf16x8 af[4], bfr[4];
    #pragma unroll
    for (int i = 0; i < 4; i++) af[i]  = *(const bf16x8*)&As[qr + i * 16 + rl][kq];
    #pragma unroll
    for (int j = 0; j < 4; j++) bfr[j] = *(const bf16x8*)&Bs[qc + j * 16 + rl][kq];

    #pragma unroll
    for (int i = 0; i < 4; i++)
      #pragma unroll
      for (int j = 0; j < 4; j++)
        acc[i][j] = __builtin_amdgcn_mfma_f32_16x16x32_bf16(af[i], bfr[j], acc[i][j], 0, 0, 0);
  }

  // epilogue: C/D layout col = lane&15, row = (lane>>4)*4 + reg  [m89/m91-verified]
  #pragma unroll
  for (int i = 0; i < 4; i++) {
    const int rowb = bn + qr + i * 16 + (lane >> 4) * 4;
    #pragma unroll
    for (int j = 0; j < 4; j++) {
      const int colp = bj + qc + j * 16 + rl;           // 0..2047 stacked column
      const float bia = actq ? bias_g[colp - 1024] : bias_d[colp];
      #pragma unroll
      for (int r = 0; r < 4; r++) {
        float v = acc[i][j][r] + bia;
        float o;
        if (!actq) o = (v > 20.f) ? v : log1pf(__expf(v));   // softplus
        else       o = v / (1.f + __expf(-v));               // silu
        outdg[(size_t)(rowb + r) * 2048 + colp] = f2bf(o);
      }
    }
  }
}

// ---- fused state update + C-contraction + residual + LayerNorm ----
// One block per row n. y region initially holds bf16 delta/gate for this row.
// DENSE lane remap: 4 consecutive lanes own the 4 s-chunks of one d, so every
// state/param load and ns store is a fully-coalesced 1KB/wave instruction
// (16 cache lines per instr instead of 64 -> 4x fewer L1 transactions).
__global__ __launch_bounds__(256) void state_ln_k(
    const float* __restrict__ x,
    const float* __restrict__ state,
    const float* __restrict__ acont,
    const float* __restrict__ Bm,
    const float* __restrict__ Cm,
    const float* __restrict__ gamma,
    const float* __restrict__ beta,
    float* __restrict__ y,
    float* __restrict__ ns)
{
  const int n = blockIdx.x;
  const int tid = threadIdx.x;
  const unsigned short* dg = (const unsigned short*)(y + (size_t)n * DIM);

  const int sc  = tid & 3;        // s-chunk 0..3 (float4 within the 16 states)
  const int dl4 = tid >> 2;       // 0..63: which d within the 64-d pass

  __shared__ float rbuf[DIM];     // residual handoff to LN phase (4KB)
  __shared__ float red[8];

  const float4* st4 = (const float4*)state;
  float4*       ns4 = (float4*)ns;
  const float4* a4  = (const float4*)acont;
  const float4* b4  = (const float4*)Bm;
  const float4* c4  = (const float4*)Cm;

  float s1 = 0.f, s2 = 0.f;
  const float lnmask = (sc == 0) ? 1.f : 0.f;

  #pragma unroll 2
  for (int q = 0; q < 16; q++) {
    const int d = q * 64 + dl4;
    const size_t nd = (size_t)n * DIM + d;

    const float xd = x[nd];                 // 4 lanes same addr: broadcast
    const float dl = bf2f(dg[d]);           // delta
    const float gt = bf2f(dg[DIM + d]);     // gate
    const float dx = dl * xd;

    float4 sv = st4[nd * 4 + sc];           // dense across wave
    float4 av = a4[(size_t)d * 4 + sc];     // dense, L2-resident
    float4 bv = b4[(size_t)d * 4 + sc];
    float4 cv = c4[(size_t)d * 4 + sc];

    float4 o;
    o.x = __expf(dl * av.x) * sv.x + dx * bv.x;
    o.y = __expf(dl * av.y) * sv.y + dx * bv.y;
    o.z = __expf(dl * av.z) * sv.z + dx * bv.z;
    o.w = __expf(dl * av.w) * sv.w + dx * bv.w;
    ns4[nd * 4 + sc] = o;                   // dense store

    float part = o.x * cv.x + o.y * cv.y + o.z * cv.z + o.w * cv.w;
    // sum over the 4-lane group (lanes 4k..4k+3 share one d)
    part += __shfl_xor(part, 1, 64);
    part += __shfl_xor(part, 2, 64);

    const float r = xd + gt * part;
    s1 += lnmask * r;
    s2 += lnmask * r * r;
    if (sc == 0) rbuf[d] = r;
  }

  // block LayerNorm reduction (only sc==0 lanes contributed; others added 0)
  #pragma unroll
  for (int off = 32; off > 0; off >>= 1) {
    s1 += __shfl_down(s1, off, 64);
    s2 += __shfl_down(s2, off, 64);
  }
  if ((tid & 63) == 0) { red[tid >> 6] = s1; red[4 + (tid >> 6)] = s2; }
  __syncthreads();  // covers: red[] visibility, rbuf visibility, all dg reads done
  const float t1 = red[0] + red[1] + red[2] + red[3];
  const float t2 = red[4] + red[5] + red[6] + red[7];
  const float mu = t1 * (1.f / (float)DIM);
  const float var = t2 * (1.f / (float)DIM) - mu * mu;
  const float rstd = rsqrtf(var + 1e-5f);

  #pragma unroll
  for (int q = 0; q < 4; q++) {
    const int d = tid + q * 256;
    const float r = rbuf[d];
    y[(size_t)n * DIM + d] = (r - mu) * rstd * gamma[d] + beta[d];
  }
}

extern "C" void kernel_launch(void* const* d_in, const int* in_sizes, int n_in,
                              void* d_out, int out_size, void* d_ws, size_t ws_size,
                              hipStream_t stream) {
  const float* x     = (const float*)d_in[0];
  const float* state = (const float*)d_in[1];
  const float* logA  = (const float*)d_in[2];
  const float* Bm    = (const float*)d_in[3];
  const float* Cm    = (const float*)d_in[4];
  const float* Wd    = (const float*)d_in[5];
  const float* bd    = (const float*)d_in[6];
  const float* Wg    = (const float*)d_in[7];
  const float* bg    = (const float*)d_in[8];
  const float* gamma = (const float*)d_in[9];
  const float* beta  = (const float*)d_in[10];

  float* y  = (float*)d_out;                         // N*D fp32 (holds bf16 delta/gate first)
  float* ns = (float*)d_out + (size_t)N_ROWS * DIM;  // N*D*S fp32

  // workspace: x_bf16 (16.8MB) + Wd_bf16 (2MB) + Wg_bf16 (2MB, contiguous => stacked W') + A_cont
  unsigned short* xb  = (unsigned short*)d_ws;
  unsigned short* wdb = xb + (size_t)N_ROWS * DIM;
  unsigned short* wgb = wdb + (size_t)DIM * DIM;     // contiguous after wdb: stacked 2048x1024
  float* acont = (float*)(wgb + (size_t)DIM * DIM);

  hipLaunchKernelGGL(cvt_bf16_k, dim3(8192), dim3(256), 0, stream, x, xb, N_ROWS * DIM / 4);
  hipLaunchKernelGGL(cvt_bf16_k, dim3(1024), dim3(256), 0, stream, Wd, wdb, DIM * DIM / 4);
  hipLaunchKernelGGL(cvt_bf16_k, dim3(1024), dim3(256), 0, stream, Wg, wgb, DIM * DIM / 4);
  hipLaunchKernelGGL(acont_k, dim3(64), dim3(256), 0, stream, logA, acont, DIM * S_DIM);

  // single merged GEMM over stacked weights: cols 0..1023 -> delta, 1024..2047 -> gate
  hipLaunchKernelGGL(gemm_act_k, dim3(16, 64), dim3(256), 0, stream, xb, wdb, bd, bg,
                     (unsigned short*)y);

  hipLaunchKernelGGL(state_ln_k, dim3(N_ROWS), dim3(256), 0, stream,
                     x, state, acont, Bm, Cm, gamma, beta, y, ns);
}